// Round 6
// baseline (809.636 us; speedup 1.0000x reference)
//
#include <hip/hip_runtime.h>
#include <hip/hip_bf16.h>

// ControllableNCA step. B=64, C=20, H=W=128. LIVING=3, ALIVE_TH=0.1, FIRE_RATE=0.5.
// Pass 1: pre-alive mask.
// Pass 2: conv(fp32) -> GEMM1 split-bf16 (fp32-grade h) -> ch3 update fp32 on VALU
//         (alive-mask channel needs fp32 accuracy: threshold discontinuity),
//         other channels via single-bf16 GEMM2. Writes unclipped x_new + ch3 plane.
// Pass 3: post-alive + life mask + clip.
// R6: LDS 78.8->53.9 KB (3 blocks/CU): p/h share one 4KB/wave buffer, p packed
//     hi|lo u32, w2 B-frags from global. Prefetched rnd/x epilogue loads.

#define BB 64
#define CC 20
#define HH 128
#define WW 128
#define LIVCH 3
#define NPIX (BB*HH*WW)

typedef __attribute__((ext_vector_type(8))) short short8;
typedef __attribute__((ext_vector_type(4))) float f32x4;
typedef __attribute__((ext_vector_type(4))) unsigned int u32x4;

#define LDS_FENCE() asm volatile("" ::: "memory")

static __device__ __forceinline__ unsigned short f2bf(float f) {
    __hip_bfloat16 h = __float2bfloat16(f);   // RNE
    return *reinterpret_cast<unsigned short*>(&h);
}
static __device__ __forceinline__ float bf2f(unsigned short u) {
    union { unsigned int i; float f; } c; c.i = ((unsigned int)u) << 16; return c.f;
}

__global__ __launch_bounds__(256) void nca_pre_mask(const float* __restrict__ x,
                                                    float* __restrict__ mpre) {
    int idx = blockIdx.x * 256 + threadIdx.x;
    int w = idx & (WW - 1);
    int h = (idx >> 7) & (HH - 1);
    int b = idx >> 14;
    const float* ch = x + ((size_t)b * CC + LIVCH) * (HH * WW);
    float m = -1e30f;
    #pragma unroll
    for (int dy = -1; dy <= 1; ++dy) {
        int y = h + dy;
        if ((unsigned)y >= HH) continue;
        #pragma unroll
        for (int dx = -1; dx <= 1; ++dx) {
            int xx = w + dx;
            if ((unsigned)xx >= WW) continue;
            m = fmaxf(m, ch[y * WW + xx]);
        }
    }
    mpre[idx] = (m > 0.1f) ? 1.0f : 0.0f;
}

// Block: 256 threads = 4 waves; 256 pixels = 2 image rows. Grid = 64*64 = 4096.
__global__ __launch_bounds__(256, 3) void nca_main_mfma(
    const float* __restrict__ x, const float* __restrict__ goal,
    const float* __restrict__ rnd, const float* __restrict__ pw,
    const float* __restrict__ w1, const float* __restrict__ b1,
    const float* __restrict__ w2, const float* __restrict__ mpre,
    float* __restrict__ xnew, float* __restrict__ ch3out) {

    __shared__ unsigned short w1h[128 * 72];   // w1 hi bf16, stride 72 (18432 B)
    __shared__ unsigned short w1l[128 * 72];   // w1 lo bf16              (18432 B)
    __shared__ unsigned int   ph_buf[4][1024]; // per-wave shared p/h tile (16384 B)
    __shared__ float edge_lds[4 * 2 * 20];     // xg at cols 63,64        (640 B)
    // total 53888 B -> 3 blocks/CU

    const int tid  = threadIdx.x;
    const int lane = tid & 63;
    const int wv   = tid >> 6;
    const int blk  = blockIdx.x;
    const int b    = blk >> 6;
    const int y0   = (blk & 63) * 2;

    // ---- stage w1 hi/lo split (Dekker: v = hi + lo + O(2^-17 v)) ----
    for (int i = tid; i < 128 * 64; i += 256) {
        int n = i >> 6, k = i & 63;
        float v = (k < 60) ? w1[n * 60 + k] : 0.0f;
        unsigned short hi = f2bf(v);
        w1h[n * 72 + k] = hi;
        w1l[n * 72 + k] = f2bf(v - bf2f(hi));
    }
    // ---- stage cross-wave edge xg values (cols 63 & 64, 4 rows, 20 ch) ----
    if (tid < 160) {
        int side = tid & 1, r = (tid >> 1) & 3, c = tid >> 3;
        int y = y0 - 1 + r, col = 63 + side;
        float v = 0.0f;
        if (y >= 0 && y < HH) {
            int gi = ((b * CC + c) << 14) + (y << 7) + col;
            float m = mpre[(b << 14) + (y << 7) + col];
            v = __builtin_fmaf(goal[gi], m, x[gi]);
        }
        edge_lds[(r * 2 + side) * 20 + c] = v;
    }
    __syncthreads();   // edge + w1 staging visible to all waves

    // ---- depthwise 3x3 conv on xg, per-lane pixel, fp32 ----
    const int y    = y0 + (tid >> 7);
    const int wcol = tid & 127;
    float p[64];
    #pragma unroll
    for (int i = 0; i < 64; ++i) p[i] = 0.0f;

    #pragma unroll
    for (int dy = -1; dy <= 1; ++dy) {
        int yy = y + dy;
        if (yy >= 0 && yy < HH) {              // wave-uniform
            int rr = dy + 1 + (tid >> 7);
            float mp = mpre[(b << 14) + (yy << 7) + wcol];
            #pragma unroll
            for (int c = 0; c < CC; ++c) {
                int gi = ((b * CC + c) << 14) + (yy << 7) + wcol;
                float v  = __builtin_fmaf(goal[gi], mp, x[gi]);
                float vm = __shfl_up(v, 1);
                float vp = __shfl_down(v, 1);
                if (lane == 0)  vm = (wcol == 0)   ? 0.0f : edge_lds[(rr * 2 + 0) * 20 + c];
                if (lane == 63) vp = (wcol == 127) ? 0.0f : edge_lds[(rr * 2 + 1) * 20 + c];
                #pragma unroll
                for (int kk = 0; kk < 3; ++kk) {
                    const int t = 3 * c + kk;
                    const float* pr = pw + t * 9 + (dy + 1) * 3;
                    p[t] = __builtin_fmaf(pr[0], vm, p[t]);
                    p[t] = __builtin_fmaf(pr[1], v,  p[t]);
                    p[t] = __builtin_fmaf(pr[2], vp, p[t]);
                }
            }
        }
    }

    // ---- pack p -> hi|lo u32 (split once, here) ----
    unsigned int php[64];
    #pragma unroll
    for (int k = 0; k < 64; ++k) {
        unsigned short hi = f2bf(p[k]);
        unsigned short lo = f2bf(p[k] - bf2f(hi));
        php[k] = (((unsigned int)hi) << 16) | lo;
    }

    const int l15 = lane & 15;
    const int l4  = lane >> 4;

    // per-lane fp32 constants from GLOBAL (exactness for mask path)
    float bias_[8], w2r3[8];
    #pragma unroll
    for (int nt = 0; nt < 8; ++nt) {
        bias_[nt] = b1[nt * 16 + l15];
        w2r3[nt]  = w2[3 * 128 + nt * 16 + l15];
    }
    // GEMM2 B-frags direct from global fp32 (w2 is 10 KB, L2-resident)
    short8 b2f[2][4];
    #pragma unroll
    for (int nt = 0; nt < 2; ++nt) {
        int o = nt * 16 + l15;
        #pragma unroll
        for (int ks = 0; ks < 4; ++ks) {
            short8 f;
            if (o < CC) {
                float4 f0 = *reinterpret_cast<const float4*>(w2 + o * 128 + ks * 32 + l4 * 8);
                float4 f1 = *reinterpret_cast<const float4*>(w2 + o * 128 + ks * 32 + l4 * 8 + 4);
                f[0] = (short)f2bf(f0.x); f[1] = (short)f2bf(f0.y);
                f[2] = (short)f2bf(f0.z); f[3] = (short)f2bf(f0.w);
                f[4] = (short)f2bf(f1.x); f[5] = (short)f2bf(f1.y);
                f[6] = (short)f2bf(f1.z); f[7] = (short)f2bf(f1.w);
            } else {
                #pragma unroll
                for (int j = 0; j < 8; ++j) f[j] = 0;
            }
            b2f[nt][ks] = f;
        }
    }

    unsigned int*   pbuf = &ph_buf[wv][0];                        // p view: [16 rows][16 slots x 4 u32]
    unsigned short* hbuf = reinterpret_cast<unsigned short*>(pbuf); // h view: [16 rows][128], XOR-swizzled

    const int hwbase = ((blk & 63) << 8) + (wv << 6);

    for (int mt = 0; mt < 4; ++mt) {
        // WAR: previous iteration's h reads (a2) precede this tile's p writes.
        LDS_FENCE();
        // ---- stage this tile's packed p rows (wave-local: lanes l4==mt own them) ----
        if (l4 == mt) {
            #pragma unroll
            for (int g = 0; g < 16; ++g) {
                u32x4 q = { php[g*4+0], php[g*4+1], php[g*4+2], php[g*4+3] };
                *reinterpret_cast<u32x4*>(pbuf + l15 * 64 + ((g ^ (l15 & 7)) << 2)) = q;
            }
        }
        LDS_FENCE();

        // ---- prefetch epilogue operands for this tile (covered by GEMM1) ----
        const int hw = hwbase + (mt << 4) + (l4 << 2);
        float4 r4 = *reinterpret_cast<const float4*>(rnd + (b << 14) + hw);
        float4 xo[2];
        #pragma unroll
        for (int nt = 0; nt < 2; ++nt) {
            int o = (nt << 4) + l15;
            if (o < CC)
                xo[nt] = *reinterpret_cast<const float4*>(x + (((b * CC + o) << 14) + hw));
        }

        // ---- A fragments from packed LDS ----
        short8 ah[2], al[2];
        #pragma unroll
        for (int ks = 0; ks < 2; ++ks) {
            int s0 = ((ks << 3) + (l4 << 1)) ^ (l15 & 7);
            int s1 = ((ks << 3) + (l4 << 1) + 1) ^ (l15 & 7);
            u32x4 q0 = *reinterpret_cast<const u32x4*>(pbuf + l15 * 64 + (s0 << 2));
            u32x4 q1 = *reinterpret_cast<const u32x4*>(pbuf + l15 * 64 + (s1 << 2));
            #pragma unroll
            for (int j = 0; j < 4; ++j) {
                ah[ks][j]     = (short)(q0[j] >> 16);
                al[ks][j]     = (short)(q0[j] & 0xffffu);
                ah[ks][4 + j] = (short)(q1[j] >> 16);
                al[ks][4 + j] = (short)(q1[j] & 0xffffu);
            }
        }

        // ---- GEMM1, 4-term split: fp32-grade h ----
        f32x4 C1[8];
        #pragma unroll
        for (int nt = 0; nt < 8; ++nt) {
            f32x4 c = { bias_[nt], bias_[nt], bias_[nt], bias_[nt] };
            #pragma unroll
            for (int ks = 0; ks < 2; ++ks) {
                const short8 bh = *reinterpret_cast<const short8*>(
                    w1h + (nt * 16 + l15) * 72 + ks * 32 + l4 * 8);
                const short8 bl = *reinterpret_cast<const short8*>(
                    w1l + (nt * 16 + l15) * 72 + ks * 32 + l4 * 8);
                c = __builtin_amdgcn_mfma_f32_16x16x32_bf16(ah[ks], bh, c, 0, 0, 0);
                c = __builtin_amdgcn_mfma_f32_16x16x32_bf16(al[ks], bh, c, 0, 0, 0);
                c = __builtin_amdgcn_mfma_f32_16x16x32_bf16(ah[ks], bl, c, 0, 0, 0);
                c = __builtin_amdgcn_mfma_f32_16x16x32_bf16(al[ks], bl, c, 0, 0, 0);
            }
            C1[nt] = c;
        }

        // ---- relu; ch3 update in fp32 (mask-exact); stage h bf16 (overlays p tile) ----
        // h writes depend on C1 <- MFMA <- p reads, so no fence needed vs p reads.
        float s[4] = {0.f, 0.f, 0.f, 0.f};
        #pragma unroll
        for (int nt = 0; nt < 8; ++nt) {
            #pragma unroll
            for (int r = 0; r < 4; ++r) {
                float hv = fmaxf(C1[nt][r], 0.0f);
                s[r] = __builtin_fmaf(w2r3[nt], hv, s[r]);
                int hrow = (l4 << 2) + r;
                hbuf[hrow * 128 + ((nt * 16 + l15) ^ ((hrow & 7) << 3))] = f2bf(hv);
            }
        }
        LDS_FENCE();   // RAW: a2 reads below consume other lanes' h writes above

        // reduce s over the 16-lane l15 group (lane bits 0..3)
        #pragma unroll
        for (int r = 0; r < 4; ++r) {
            s[r] += __shfl_xor(s[r], 1, 64);
            s[r] += __shfl_xor(s[r], 2, 64);
            s[r] += __shfl_xor(s[r], 4, 64);
            s[r] += __shfl_xor(s[r], 8, 64);
        }

        // ---- GEMM2 single-bf16 (values only; ch3 overridden below) ----
        f32x4 C2[2];
        C2[0] = (f32x4){0.f, 0.f, 0.f, 0.f};
        C2[1] = (f32x4){0.f, 0.f, 0.f, 0.f};
        #pragma unroll
        for (int ks = 0; ks < 4; ++ks) {
            int col0 = (ks * 32 + l4 * 8) ^ ((l15 & 7) << 3);
            short8 a2 = *reinterpret_cast<const short8*>(hbuf + l15 * 128 + col0);
            C2[0] = __builtin_amdgcn_mfma_f32_16x16x32_bf16(a2, b2f[0][ks], C2[0], 0, 0, 0);
            C2[1] = __builtin_amdgcn_mfma_f32_16x16x32_bf16(a2, b2f[1][ks], C2[1], 0, 0, 0);
        }

        // ---- epilogue: x_new = x + rand_mask * out ----
        float rm0 = (r4.x < 0.5f) ? 1.0f : 0.0f;
        float rm1 = (r4.y < 0.5f) ? 1.0f : 0.0f;
        float rm2 = (r4.z < 0.5f) ? 1.0f : 0.0f;
        float rm3 = (r4.w < 0.5f) ? 1.0f : 0.0f;
        #pragma unroll
        for (int nt = 0; nt < 2; ++nt) {
            int o = (nt << 4) + l15;
            if (o < CC) {
                const bool isliv = (nt == 0) && (l15 == LIVCH);
                float u0 = isliv ? s[0] : C2[nt][0];
                float u1 = isliv ? s[1] : C2[nt][1];
                float u2 = isliv ? s[2] : C2[nt][2];
                float u3 = isliv ? s[3] : C2[nt][3];
                int gi = ((b * CC + o) << 14) + hw;
                float4 vo;
                vo.x = __builtin_fmaf(rm0, u0, xo[nt].x);
                vo.y = __builtin_fmaf(rm1, u1, xo[nt].y);
                vo.z = __builtin_fmaf(rm2, u2, xo[nt].z);
                vo.w = __builtin_fmaf(rm3, u3, xo[nt].w);
                *reinterpret_cast<float4*>(xnew + gi) = vo;
                if (isliv)
                    *reinterpret_cast<float4*>(ch3out + (b << 14) + hw) = vo;
            }
        }
    }
}

__global__ __launch_bounds__(256) void nca_finalize(const float* __restrict__ ch3,
                                                    const float* __restrict__ mpre,
                                                    float* __restrict__ xnew) {
    int idx = blockIdx.x * 256 + threadIdx.x;
    int w = idx & (WW - 1);
    int h = (idx >> 7) & (HH - 1);
    int b = idx >> 14;
    const float* plane = ch3 + b * (HH * WW);
    float m = -1e30f;
    #pragma unroll
    for (int dy = -1; dy <= 1; ++dy) {
        int y = h + dy;
        if ((unsigned)y >= HH) continue;
        #pragma unroll
        for (int dx = -1; dx <= 1; ++dx) {
            int xx = w + dx;
            if ((unsigned)xx >= WW) continue;
            m = fmaxf(m, plane[y * WW + xx]);
        }
    }
    bool post = m > 0.1f;
    bool pre = mpre[idx] > 0.5f;
    float life = (pre && post) ? 1.0f : 0.0f;

    size_t base_b = (size_t)b * CC * (HH * WW);
    int pixoff = h * WW + w;
    #pragma unroll
    for (int c = 0; c < CC; ++c) {
        size_t o = base_b + (size_t)c * (HH * WW) + pixoff;
        float v = xnew[o] * life;
        v = fminf(fmaxf(v, -10.0f), 10.0f);
        xnew[o] = v;
    }
}

extern "C" void kernel_launch(void* const* d_in, const int* in_sizes, int n_in,
                              void* d_out, int out_size, void* d_ws, size_t ws_size,
                              hipStream_t stream) {
    const float* x    = (const float*)d_in[0];
    const float* goal = (const float*)d_in[1];
    const float* rnd  = (const float*)d_in[2];
    const float* pw   = (const float*)d_in[3];
    const float* w1   = (const float*)d_in[4];
    const float* b1   = (const float*)d_in[5];
    const float* w2   = (const float*)d_in[6];
    float* out = (float*)d_out;

    float* mpre = (float*)d_ws;              // NPIX floats
    float* ch3  = mpre + NPIX;               // NPIX floats

    dim3 blk(256), grd(NPIX / 256);
    hipLaunchKernelGGL(nca_pre_mask, grd, blk, 0, stream, x, mpre);
    hipLaunchKernelGGL(nca_main_mfma, dim3(BB * HH / 2), blk, 0, stream,
                       x, goal, rnd, pw, w1, b1, w2, mpre, out, ch3);
    hipLaunchKernelGGL(nca_finalize, grd, blk, 0, stream, ch3, mpre, out);
}

// Round 7
// 496.183 us; speedup vs baseline: 1.6317x; 1.6317x over previous
//
#include <hip/hip_runtime.h>
#include <hip/hip_bf16.h>

// ControllableNCA step. B=64, C=20, H=W=128. LIVING=3, ALIVE_TH=0.1, FIRE_RATE=0.5.
// Pass 1: pre-alive mask.
// Pass 2: conv(fp32) -> GEMM1 split-bf16 (fp32-grade h) -> ch3 update fp32 on VALU
//         (alive-mask channel needs fp32 accuracy: threshold discontinuity),
//         other channels via single-bf16 GEMM2. Writes unclipped x_new + ch3 plane.
// Pass 3: post-alive + life mask + clip.
// R7: fp32 p staging + per-mt split (NO packed reg array -> no spill, cf. R6),
//     launch_bounds(256,2) (VGPR cap 256), LDS 50.8 KB -> 3 blocks/CU via
//     shared p/h buffer + unpadded XOR-swizzled w1 + w2 frags from global.

#define BB 64
#define CC 20
#define HH 128
#define WW 128
#define LIVCH 3
#define NPIX (BB*HH*WW)

typedef __attribute__((ext_vector_type(8))) short short8;
typedef __attribute__((ext_vector_type(4))) float f32x4;

#define LDS_FENCE() asm volatile("" ::: "memory")

static __device__ __forceinline__ unsigned short f2bf(float f) {
    __hip_bfloat16 h = __float2bfloat16(f);   // RNE
    return *reinterpret_cast<unsigned short*>(&h);
}
static __device__ __forceinline__ float bf2f(unsigned short u) {
    union { unsigned int i; float f; } c; c.i = ((unsigned int)u) << 16; return c.f;
}

__global__ __launch_bounds__(256) void nca_pre_mask(const float* __restrict__ x,
                                                    float* __restrict__ mpre) {
    int idx = blockIdx.x * 256 + threadIdx.x;
    int w = idx & (WW - 1);
    int h = (idx >> 7) & (HH - 1);
    int b = idx >> 14;
    const float* ch = x + ((size_t)b * CC + LIVCH) * (HH * WW);
    float m = -1e30f;
    #pragma unroll
    for (int dy = -1; dy <= 1; ++dy) {
        int y = h + dy;
        if ((unsigned)y >= HH) continue;
        #pragma unroll
        for (int dx = -1; dx <= 1; ++dx) {
            int xx = w + dx;
            if ((unsigned)xx >= WW) continue;
            m = fmaxf(m, ch[y * WW + xx]);
        }
    }
    mpre[idx] = (m > 0.1f) ? 1.0f : 0.0f;
}

// Block: 256 threads = 4 waves; 256 pixels = 2 image rows. Grid = 64*64 = 4096.
__global__ __launch_bounds__(256, 2) void nca_main_mfma(
    const float* __restrict__ x, const float* __restrict__ goal,
    const float* __restrict__ rnd, const float* __restrict__ pw,
    const float* __restrict__ w1, const float* __restrict__ b1,
    const float* __restrict__ w2, const float* __restrict__ mpre,
    float* __restrict__ xnew, float* __restrict__ ch3out) {

    // w1 hi/lo: [128][64] bf16, UNPADDED, 16B-chunk XOR swizzle:
    //   elem (n,k) at short index n*64 + (((k>>3)^(n&7))<<3) + (k&7)
    // -> even 8-lanes-per-bank on b128 reads (the wave64 floor), 0 pad bytes.
    __shared__ unsigned short w1h[128 * 64];   // 16384 B
    __shared__ unsigned short w1l[128 * 64];   // 16384 B
    // per-wave shared p/h tile: p view [16][68] f32, h view [16][136] bf16 (same 272B row stride)
    __shared__ float ph_buf[4][16 * 68];       // 17408 B
    __shared__ float edge_lds[4 * 2 * 20];     // 640 B
    // total 50816 B -> 3 blocks/CU

    const int tid  = threadIdx.x;
    const int lane = tid & 63;
    const int wv   = tid >> 6;
    const int blk  = blockIdx.x;
    const int b    = blk >> 6;
    const int y0   = (blk & 63) * 2;

    // ---- stage w1 hi/lo split (Dekker: v = hi + lo + O(2^-17 v)), swizzled ----
    for (int i = tid; i < 128 * 64; i += 256) {
        int n = i >> 6, k = i & 63;
        float v = (k < 60) ? w1[n * 60 + k] : 0.0f;
        unsigned short hi = f2bf(v);
        int si = (n << 6) + ((((k >> 3) ^ (n & 7)) << 3)) + (k & 7);
        w1h[si] = hi;
        w1l[si] = f2bf(v - bf2f(hi));
    }
    // ---- stage cross-wave edge xg values (cols 63 & 64, 4 rows, 20 ch) ----
    if (tid < 160) {
        int side = tid & 1, r = (tid >> 1) & 3, c = tid >> 3;
        int y = y0 - 1 + r, col = 63 + side;
        float v = 0.0f;
        if (y >= 0 && y < HH) {
            int gi = ((b * CC + c) << 14) + (y << 7) + col;
            float m = mpre[(b << 14) + (y << 7) + col];
            v = __builtin_fmaf(goal[gi], m, x[gi]);
        }
        edge_lds[(r * 2 + side) * 20 + c] = v;
    }
    __syncthreads();   // edge + w1 staging visible to all waves

    // ---- depthwise 3x3 conv on xg, per-lane pixel, fp32 ----
    const int y    = y0 + (tid >> 7);
    const int wcol = tid & 127;
    float p[64];
    #pragma unroll
    for (int i = 0; i < 64; ++i) p[i] = 0.0f;

    #pragma unroll
    for (int dy = -1; dy <= 1; ++dy) {
        int yy = y + dy;
        if (yy >= 0 && yy < HH) {              // wave-uniform
            int rr = dy + 1 + (tid >> 7);
            float mp = mpre[(b << 14) + (yy << 7) + wcol];
            #pragma unroll
            for (int c = 0; c < CC; ++c) {
                int gi = ((b * CC + c) << 14) + (yy << 7) + wcol;
                float v  = __builtin_fmaf(goal[gi], mp, x[gi]);
                float vm = __shfl_up(v, 1);
                float vp = __shfl_down(v, 1);
                if (lane == 0)  vm = (wcol == 0)   ? 0.0f : edge_lds[(rr * 2 + 0) * 20 + c];
                if (lane == 63) vp = (wcol == 127) ? 0.0f : edge_lds[(rr * 2 + 1) * 20 + c];
                #pragma unroll
                for (int kk = 0; kk < 3; ++kk) {
                    const int t = 3 * c + kk;
                    const float* pr = pw + t * 9 + (dy + 1) * 3;
                    p[t] = __builtin_fmaf(pr[0], vm, p[t]);
                    p[t] = __builtin_fmaf(pr[1], v,  p[t]);
                    p[t] = __builtin_fmaf(pr[2], vp, p[t]);
                }
            }
        }
    }

    const int l15 = lane & 15;
    const int l4  = lane >> 4;

    // per-lane fp32 constants from GLOBAL (exactness for mask path)
    float bias_[8], w2r3[8];
    #pragma unroll
    for (int nt = 0; nt < 8; ++nt) {
        bias_[nt] = b1[nt * 16 + l15];
        w2r3[nt]  = w2[3 * 128 + nt * 16 + l15];
    }
    // GEMM2 B-frags direct from global fp32 (w2 is 10 KB, L2-resident)
    short8 b2f[2][4];
    #pragma unroll
    for (int nt = 0; nt < 2; ++nt) {
        int o = nt * 16 + l15;
        #pragma unroll
        for (int ks = 0; ks < 4; ++ks) {
            short8 f;
            if (o < CC) {
                float4 f0 = *reinterpret_cast<const float4*>(w2 + o * 128 + ks * 32 + l4 * 8);
                float4 f1 = *reinterpret_cast<const float4*>(w2 + o * 128 + ks * 32 + l4 * 8 + 4);
                f[0] = (short)f2bf(f0.x); f[1] = (short)f2bf(f0.y);
                f[2] = (short)f2bf(f0.z); f[3] = (short)f2bf(f0.w);
                f[4] = (short)f2bf(f1.x); f[5] = (short)f2bf(f1.y);
                f[6] = (short)f2bf(f1.z); f[7] = (short)f2bf(f1.w);
            } else {
                #pragma unroll
                for (int j = 0; j < 8; ++j) f[j] = 0;
            }
            b2f[nt][ks] = f;
        }
    }

    float*          pbuf = &ph_buf[wv][0];                          // [16][68] f32
    unsigned short* hbuf = reinterpret_cast<unsigned short*>(pbuf); // [16][136] bf16

    const int hwbase = ((blk & 63) << 8) + (wv << 6);

    for (int mt = 0; mt < 4; ++mt) {
        // WAR: previous iteration's h reads (a2) precede this tile's p writes.
        LDS_FENCE();
        // ---- stage this tile's p rows fp32 (wave-local: lanes l4==mt own them) ----
        if (l4 == mt) {
            #pragma unroll
            for (int g = 0; g < 16; ++g) {
                f32x4 t = { p[g*4+0], p[g*4+1], p[g*4+2], p[g*4+3] };
                *reinterpret_cast<f32x4*>(pbuf + l15 * 68 + g * 4) = t;
            }
        }
        LDS_FENCE();

        // ---- prefetch epilogue operands for this tile (covered by GEMM1) ----
        const int hw = hwbase + (mt << 4) + (l4 << 2);
        float4 r4 = *reinterpret_cast<const float4*>(rnd + (b << 14) + hw);
        float4 xo[2];
        #pragma unroll
        for (int nt = 0; nt < 2; ++nt) {
            int o = (nt << 4) + l15;
            if (o < CC)
                xo[nt] = *reinterpret_cast<const float4*>(x + (((b * CC + o) << 14) + hw));
        }

        // ---- A fragments: read fp32, split hi/lo in-register ----
        short8 ah[2], al[2];
        #pragma unroll
        for (int ks = 0; ks < 2; ++ks) {
            f32x4 u0 = *reinterpret_cast<const f32x4*>(pbuf + l15 * 68 + ks * 32 + l4 * 8);
            f32x4 u1 = *reinterpret_cast<const f32x4*>(pbuf + l15 * 68 + ks * 32 + l4 * 8 + 4);
            #pragma unroll
            for (int j = 0; j < 4; ++j) {
                unsigned short h0 = f2bf(u0[j]);
                ah[ks][j]     = (short)h0;
                al[ks][j]     = (short)f2bf(u0[j] - bf2f(h0));
                unsigned short h1 = f2bf(u1[j]);
                ah[ks][4 + j] = (short)h1;
                al[ks][4 + j] = (short)f2bf(u1[j] - bf2f(h1));
            }
        }

        // ---- GEMM1, 4-term split: fp32-grade h ----
        f32x4 C1[8];
        #pragma unroll
        for (int nt = 0; nt < 8; ++nt) {
            f32x4 c = { bias_[nt], bias_[nt], bias_[nt], bias_[nt] };
            #pragma unroll
            for (int ks = 0; ks < 2; ++ks) {
                const int n = nt * 16 + l15;
                const int chunk = (((ks << 2) + l4) ^ (n & 7)) << 3;
                const short8 bh = *reinterpret_cast<const short8*>(w1h + (n << 6) + chunk);
                const short8 bl = *reinterpret_cast<const short8*>(w1l + (n << 6) + chunk);
                c = __builtin_amdgcn_mfma_f32_16x16x32_bf16(ah[ks], bh, c, 0, 0, 0);
                c = __builtin_amdgcn_mfma_f32_16x16x32_bf16(al[ks], bh, c, 0, 0, 0);
                c = __builtin_amdgcn_mfma_f32_16x16x32_bf16(ah[ks], bl, c, 0, 0, 0);
                c = __builtin_amdgcn_mfma_f32_16x16x32_bf16(al[ks], bl, c, 0, 0, 0);
            }
            C1[nt] = c;
        }

        // ---- relu; ch3 update in fp32 (mask-exact); stage h bf16 (overlays p tile) ----
        // h writes depend on C1 <- MFMA <- p reads: data dependency orders them.
        float s[4] = {0.f, 0.f, 0.f, 0.f};
        #pragma unroll
        for (int nt = 0; nt < 8; ++nt) {
            #pragma unroll
            for (int r = 0; r < 4; ++r) {
                float hv = fmaxf(C1[nt][r], 0.0f);
                s[r] = __builtin_fmaf(w2r3[nt], hv, s[r]);
                int hrow = (l4 << 2) + r;
                hbuf[hrow * 136 + ((nt * 16 + l15) ^ ((hrow & 7) << 3))] = f2bf(hv);
            }
        }
        LDS_FENCE();   // RAW: a2 reads below consume other lanes' h writes above

        // reduce s over the 16-lane l15 group (lane bits 0..3)
        #pragma unroll
        for (int r = 0; r < 4; ++r) {
            s[r] += __shfl_xor(s[r], 1, 64);
            s[r] += __shfl_xor(s[r], 2, 64);
            s[r] += __shfl_xor(s[r], 4, 64);
            s[r] += __shfl_xor(s[r], 8, 64);
        }

        // ---- GEMM2 single-bf16 (values only; ch3 overridden below) ----
        f32x4 C2[2];
        C2[0] = (f32x4){0.f, 0.f, 0.f, 0.f};
        C2[1] = (f32x4){0.f, 0.f, 0.f, 0.f};
        #pragma unroll
        for (int ks = 0; ks < 4; ++ks) {
            int col0 = (ks * 32 + l4 * 8) ^ ((l15 & 7) << 3);
            short8 a2 = *reinterpret_cast<const short8*>(hbuf + l15 * 136 + col0);
            C2[0] = __builtin_amdgcn_mfma_f32_16x16x32_bf16(a2, b2f[0][ks], C2[0], 0, 0, 0);
            C2[1] = __builtin_amdgcn_mfma_f32_16x16x32_bf16(a2, b2f[1][ks], C2[1], 0, 0, 0);
        }

        // ---- epilogue: x_new = x + rand_mask * out ----
        float rm0 = (r4.x < 0.5f) ? 1.0f : 0.0f;
        float rm1 = (r4.y < 0.5f) ? 1.0f : 0.0f;
        float rm2 = (r4.z < 0.5f) ? 1.0f : 0.0f;
        float rm3 = (r4.w < 0.5f) ? 1.0f : 0.0f;
        #pragma unroll
        for (int nt = 0; nt < 2; ++nt) {
            int o = (nt << 4) + l15;
            if (o < CC) {
                const bool isliv = (nt == 0) && (l15 == LIVCH);
                float u0 = isliv ? s[0] : C2[nt][0];
                float u1 = isliv ? s[1] : C2[nt][1];
                float u2 = isliv ? s[2] : C2[nt][2];
                float u3 = isliv ? s[3] : C2[nt][3];
                int gi = ((b * CC + o) << 14) + hw;
                float4 vo;
                vo.x = __builtin_fmaf(rm0, u0, xo[nt].x);
                vo.y = __builtin_fmaf(rm1, u1, xo[nt].y);
                vo.z = __builtin_fmaf(rm2, u2, xo[nt].z);
                vo.w = __builtin_fmaf(rm3, u3, xo[nt].w);
                *reinterpret_cast<float4*>(xnew + gi) = vo;
                if (isliv)
                    *reinterpret_cast<float4*>(ch3out + (b << 14) + hw) = vo;
            }
        }
    }
}

__global__ __launch_bounds__(256) void nca_finalize(const float* __restrict__ ch3,
                                                    const float* __restrict__ mpre,
                                                    float* __restrict__ xnew) {
    int idx = blockIdx.x * 256 + threadIdx.x;
    int w = idx & (WW - 1);
    int h = (idx >> 7) & (HH - 1);
    int b = idx >> 14;
    const float* plane = ch3 + b * (HH * WW);
    float m = -1e30f;
    #pragma unroll
    for (int dy = -1; dy <= 1; ++dy) {
        int y = h + dy;
        if ((unsigned)y >= HH) continue;
        #pragma unroll
        for (int dx = -1; dx <= 1; ++dx) {
            int xx = w + dx;
            if ((unsigned)xx >= WW) continue;
            m = fmaxf(m, plane[y * WW + xx]);
        }
    }
    bool post = m > 0.1f;
    bool pre = mpre[idx] > 0.5f;
    float life = (pre && post) ? 1.0f : 0.0f;

    size_t base_b = (size_t)b * CC * (HH * WW);
    int pixoff = h * WW + w;
    #pragma unroll
    for (int c = 0; c < CC; ++c) {
        size_t o = base_b + (size_t)c * (HH * WW) + pixoff;
        float v = xnew[o] * life;
        v = fminf(fmaxf(v, -10.0f), 10.0f);
        xnew[o] = v;
    }
}

extern "C" void kernel_launch(void* const* d_in, const int* in_sizes, int n_in,
                              void* d_out, int out_size, void* d_ws, size_t ws_size,
                              hipStream_t stream) {
    const float* x    = (const float*)d_in[0];
    const float* goal = (const float*)d_in[1];
    const float* rnd  = (const float*)d_in[2];
    const float* pw   = (const float*)d_in[3];
    const float* w1   = (const float*)d_in[4];
    const float* b1   = (const float*)d_in[5];
    const float* w2   = (const float*)d_in[6];
    float* out = (float*)d_out;

    float* mpre = (float*)d_ws;              // NPIX floats
    float* ch3  = mpre + NPIX;               // NPIX floats

    dim3 blk(256), grd(NPIX / 256);
    hipLaunchKernelGGL(nca_pre_mask, grd, blk, 0, stream, x, mpre);
    hipLaunchKernelGGL(nca_main_mfma, dim3(BB * HH / 2), blk, 0, stream,
                       x, goal, rnd, pw, w1, b1, w2, mpre, out, ch3);
    hipLaunchKernelGGL(nca_finalize, grd, blk, 0, stream, ch3, mpre, out);
}